// Round 5
// baseline (163.380 us; speedup 1.0000x reference)
//
#include <hip/hip_runtime.h>
#include <stdint.h>

#define DM 1024     // D_MODEL
#define NH 16       // NUM_HEADS
#define DK 64       // D_K

typedef __attribute__((ext_vector_type(8))) __bf16 bf16x8;
typedef __attribute__((ext_vector_type(4))) float f32x4;

__device__ __forceinline__ float bf2f(unsigned short u) {
    union { uint32_t i; float f; } x; x.i = ((uint32_t)u) << 16; return x.f;
}
__device__ __forceinline__ unsigned short f2bf(float f) {
    union { float f; uint32_t i; } x; x.f = f;
    uint32_t r = x.i + 0x7fffu + ((x.i >> 16) & 1u);   // RNE
    return (unsigned short)(r >> 16);
}

__device__ __forceinline__ void gl2lds16(const void* g, void* l) {
    __builtin_amdgcn_global_load_lds(
        (const __attribute__((address_space(1))) void*)g,
        (__attribute__((address_space(3))) void*)l, 16, 0, 0);
}

__device__ __forceinline__ f32x4 mfma_bf16(bf16x8 a, bf16x8 b, f32x4 c) {
    return __builtin_amdgcn_mfma_f32_16x16x32_bf16(a, b, c, 0, 0, 0);
}

template<int N> __device__ __forceinline__ void waitvm() {
    if constexpr (N == 8)      asm volatile("s_waitcnt vmcnt(8)" ::: "memory");
    else if constexpr (N == 4) asm volatile("s_waitcnt vmcnt(4)" ::: "memory");
    else if constexpr (N == 0) asm volatile("s_waitcnt vmcnt(0)" ::: "memory");
    else                       asm volatile("" ::: "memory");   // compiler fence only
}

// ---------------------------------------------------------------------------
// fp32 -> bf16 conversion, 15 segments of exactly 1M floats (2^18 float4).
// ---------------------------------------------------------------------------
struct CvtArgs {
    const float* src[15];
    unsigned short* dst[15];
};

__global__ __launch_bounds__(256) void cvt15(CvtArgs a) {
    const int t = blockIdx.x * 256 + threadIdx.x;
    const int seg = t >> 18;
    const int off = t & 0x3ffff;
    const float4 v = reinterpret_cast<const float4*>(a.src[seg])[off];
    ushort4 o;
    o.x = f2bf(v.x); o.y = f2bf(v.y); o.z = f2bf(v.z); o.w = f2bf(v.w);
    reinterpret_cast<ushort4*>(a.dst[seg])[off] = o;
}

// ---------------------------------------------------------------------------
// 8-phase 256x256 NT GEMM (bf16 in / bf16 out + bias), batched over z.
// 512 threads = 8 waves (2Mx4N), BK=64 staged as 4 half-tiles [256 rows][32 k].
// LDS XOR-swizzle (rule #21, both-sides): byte bits 4-5 ^= row bits 2-3.
//   write side: linear LDS dest + lane-permuted global source
//               (tid' = tid ^ ((tid>>4)&3))
//   read side:  per-lane constant XOR swz = (l15&12)<<2
// Post-swizzle each 16-lane group covers all 8 bank-quads 2x (2-way = free).
// Counted vmcnt(8) at phases 2/4; raw barriers; setprio around MFMA; the
// ds_read->MFMA waits are left to the compiler (fine-grained lgkmcnt).
// ---------------------------------------------------------------------------
struct Gemm8Args {
    const unsigned short* A[3];
    const unsigned short* W[3];
    const float* bias[3];
    unsigned short* C[3];
};

__device__ __forceinline__ void stage_half2(const unsigned short* src, int ldg,
                                            unsigned short* dst, int tid) {
    gl2lds16(src,                        dst + (size_t)tid * 8);
    gl2lds16(src + (size_t)ldg * 128,    dst + 4096 + (size_t)tid * 8);
}

template<bool I1, bool I2, bool I3, bool I4, int W2, int W4>
__device__ __forceinline__ void tile_step(
    int t, int K, const unsigned short* aSrc, const unsigned short* bSrc,
    unsigned short* ldsBase, int tid, int aOffB, int bOffB,
    bf16x8 (&af)[8], f32x4 (&acc)[8][4])
{
    const int par = t & 1;
    unsigned short* Lw = ldsBase + par * 32768;         // element ptr (stage dst)
    unsigned short* Ln = ldsBase + (par ^ 1) * 32768;
    const char* L  = (const char*)Lw;
    const char* A0 = L;                 // A, k-half 0   (16384 B each)
    const char* A1 = L + 16384;         // A, k-half 1
    const char* B0 = L + 32768;         // B, k-half 0
    const char* B1 = L + 49152;         // B, k-half 1

    // ---- phase 1: kk=0, n-half 0; stage (t+1).A1
    {
        bf16x8 b0 = *reinterpret_cast<const bf16x8*>(B0 + 0 * 1024 + bOffB);
        bf16x8 b1 = *reinterpret_cast<const bf16x8*>(B0 + 1 * 1024 + bOffB);
        #pragma unroll
        for (int m = 0; m < 8; ++m)
            af[m] = *reinterpret_cast<const bf16x8*>(A0 + m * 1024 + aOffB);
        if (I1) stage_half2(aSrc + (size_t)(t + 1) * 64 + 32, K, Ln + 8192, tid);
        __builtin_amdgcn_s_barrier();
        __builtin_amdgcn_s_setprio(1);
        #pragma unroll
        for (int m = 0; m < 8; ++m) {
            acc[m][0] = mfma_bf16(af[m], b0, acc[m][0]);
            acc[m][1] = mfma_bf16(af[m], b1, acc[m][1]);
        }
        __builtin_amdgcn_s_setprio(0);
        waitvm<-1>();
        __builtin_amdgcn_s_barrier();
    }
    // ---- phase 2: kk=0, n-half 1; stage (t+1).B1
    {
        bf16x8 b0 = *reinterpret_cast<const bf16x8*>(B0 + 2 * 1024 + bOffB);
        bf16x8 b1 = *reinterpret_cast<const bf16x8*>(B0 + 3 * 1024 + bOffB);
        if (I2) stage_half2(bSrc + (size_t)(t + 1) * 64 + 32, K, Ln + 24576, tid);
        __builtin_amdgcn_s_barrier();
        __builtin_amdgcn_s_setprio(1);
        #pragma unroll
        for (int m = 0; m < 8; ++m) {
            acc[m][2] = mfma_bf16(af[m], b0, acc[m][2]);
            acc[m][3] = mfma_bf16(af[m], b1, acc[m][3]);
        }
        __builtin_amdgcn_s_setprio(0);
        waitvm<W2>();
        __builtin_amdgcn_s_barrier();
    }
    // ---- phase 3: kk=1, n-half 0; stage (t+2).A0
    {
        bf16x8 b0 = *reinterpret_cast<const bf16x8*>(B1 + 0 * 1024 + bOffB);
        bf16x8 b1 = *reinterpret_cast<const bf16x8*>(B1 + 1 * 1024 + bOffB);
        #pragma unroll
        for (int m = 0; m < 8; ++m)
            af[m] = *reinterpret_cast<const bf16x8*>(A1 + m * 1024 + aOffB);
        if (I3) stage_half2(aSrc + (size_t)(t + 2) * 64, K, Lw, tid);
        __builtin_amdgcn_s_barrier();
        __builtin_amdgcn_s_setprio(1);
        #pragma unroll
        for (int m = 0; m < 8; ++m) {
            acc[m][0] = mfma_bf16(af[m], b0, acc[m][0]);
            acc[m][1] = mfma_bf16(af[m], b1, acc[m][1]);
        }
        __builtin_amdgcn_s_setprio(0);
        waitvm<-1>();
        __builtin_amdgcn_s_barrier();
    }
    // ---- phase 4: kk=1, n-half 1; stage (t+2).B0
    {
        bf16x8 b0 = *reinterpret_cast<const bf16x8*>(B1 + 2 * 1024 + bOffB);
        bf16x8 b1 = *reinterpret_cast<const bf16x8*>(B1 + 3 * 1024 + bOffB);
        if (I4) stage_half2(bSrc + (size_t)(t + 2) * 64, K, Lw + 16384, tid);
        __builtin_amdgcn_s_barrier();
        __builtin_amdgcn_s_setprio(1);
        #pragma unroll
        for (int m = 0; m < 8; ++m) {
            acc[m][2] = mfma_bf16(af[m], b0, acc[m][2]);
            acc[m][3] = mfma_bf16(af[m], b1, acc[m][3]);
        }
        __builtin_amdgcn_s_setprio(0);
        waitvm<W4>();
        __builtin_amdgcn_s_barrier();
    }
}

__global__ __launch_bounds__(512, 2) void gemm8_nt_bf16(Gemm8Args g, int M, int N, int K)
{
    const unsigned short* __restrict__ A  = g.A[blockIdx.z];
    const unsigned short* __restrict__ Bw = g.W[blockIdx.z];
    const float* __restrict__ bias = g.bias[blockIdx.z];
    unsigned short* __restrict__ C = g.C[blockIdx.z];

    __shared__ unsigned short lds[2][4][8192];   // [parity][A0,A1,B0,B1][256*32]

    const int tid  = threadIdx.x;
    const int lane = tid & 63;
    const int w    = tid >> 6;          // wave 0..7
    const int wr   = w >> 2, wc = w & 3;
    const int l15  = lane & 15, q8 = (lane >> 4) * 8;
    const int row0 = blockIdx.y * 256;
    const int col0 = blockIdx.x * 256;

    // write-side swizzle: lane permutation of the global source, LDS linear
    const int tidp = tid ^ ((tid >> 4) & 3);
    const unsigned short* aSrc = A  + (size_t)(row0 + (tidp >> 2)) * K + (tidp & 3) * 8;
    const unsigned short* bSrc = Bw + (size_t)(col0 + (tidp >> 2)) * K + (tidp & 3) * 8;
    unsigned short* ldsBase = &lds[0][0][0];

    // read-side swizzle: per-lane constant XOR on byte offset (row bits 2-3)
    const int swz = (l15 & 12) << 2;
    const int aOffB = (((wr * 128 + l15) * 32 + q8) * 2) ^ swz;   // + m*1024 B
    const int bOffB = (((wc * 64  + l15) * 32 + q8) * 2) ^ swz;   // + n*1024 B

    f32x4 acc[8][4];
    #pragma unroll
    for (int m = 0; m < 8; ++m)
        #pragma unroll
        for (int n = 0; n < 4; ++n)
            acc[m][n] = (f32x4){0.f, 0.f, 0.f, 0.f};
    bf16x8 af[8];

    const int NT = K >> 6;   // 64-wide K tiles (16 for K=1024)

    // prologue: t0.A0, t0.B0, t0.A1, t0.B1, t1.A0, t1.B0  (12 loads/thread-pair)
    stage_half2(aSrc,      K, ldsBase,             tid);
    stage_half2(bSrc,      K, ldsBase + 16384,     tid);
    stage_half2(aSrc + 32, K, ldsBase + 8192,      tid);
    stage_half2(bSrc + 32, K, ldsBase + 24576,     tid);
    stage_half2(aSrc + 64, K, ldsBase + 32768,     tid);
    stage_half2(bSrc + 64, K, ldsBase + 32768 + 16384, tid);
    waitvm<8>();
    __builtin_amdgcn_s_barrier();
    __builtin_amdgcn_sched_barrier(0);

    for (int t = 0; t < NT - 2; ++t)
        tile_step<true, true, true, true, 8, 8>(t, K, aSrc, bSrc, ldsBase, tid, aOffB, bOffB, af, acc);
    tile_step<true, true, false, false, 8, 4>(NT - 2, K, aSrc, bSrc, ldsBase, tid, aOffB, bOffB, af, acc);
    tile_step<false, false, false, false, 0, -1>(NT - 1, K, aSrc, bSrc, ldsBase, tid, aOffB, bOffB, af, acc);

    // epilogue: C/D layout col=lane&15, row=(lane>>4)*4+reg
    const int cr = (lane >> 4) * 4, cc = lane & 15;
    #pragma unroll
    for (int n = 0; n < 4; ++n) {
        const int col = col0 + wc * 64 + n * 16 + cc;
        const float bv = bias[col];
        #pragma unroll
        for (int m = 0; m < 8; ++m) {
            const int rowb = row0 + wr * 128 + m * 16 + cr;
            #pragma unroll
            for (int r = 0; r < 4; ++r)
                C[(size_t)(rowb + r) * N + col] = f2bf(acc[m][n][r] + bv);
        }
    }
}

// ---------------------------------------------------------------------------
// 2-phase NT GEMM (verified structure), fp32 out + bias, per-batch W/bias
// selected by row (out = Qp @ Wf[b]^T + bias2[b]).
// ---------------------------------------------------------------------------
template<int BM, int BN>
__global__ __launch_bounds__(256) void gemm_nt_final(
    const unsigned short* __restrict__ A,
    const unsigned short* __restrict__ W0, const unsigned short* __restrict__ W1,
    const float* __restrict__ bias0, const float* __restrict__ bias1,
    float* __restrict__ C, int M, int N, int K, int rowSplit)
{
    constexpr int FM = BM / 32;
    constexpr int FN = BN / 32;

    __shared__ unsigned short As[BM * 64];
    __shared__ unsigned short Bs[BN * 64];

    const int tid  = threadIdx.x;
    const int lane = tid & 63;
    const int w    = tid >> 6;
    const int wr   = w >> 1, wc = w & 1;
    const int row0 = blockIdx.y * BM;
    const int col0 = blockIdx.x * BN;
    const bool hi  = row0 >= rowSplit;
    const unsigned short* __restrict__ Bw = hi ? W1 : W0;
    const float* __restrict__ bias = hi ? bias1 : bias0;

    f32x4 acc[FM][FN];
    #pragma unroll
    for (int m = 0; m < FM; ++m)
        #pragma unroll
        for (int n = 0; n < FN; ++n)
            acc[m][n] = (f32x4){0.f, 0.f, 0.f, 0.f};

    const int srow = lane >> 3;
    const int scol = (lane & 7) * 8;

    for (int kt = 0; kt < K; kt += 64) {
        #pragma unroll
        for (int i = 0; i < BM / 32; ++i) {
            const int stripe = w * (BM / 32) + i;
            const int r = stripe * 8 + srow;
            gl2lds16(A + (size_t)(row0 + r) * K + kt + scol, &As[stripe * 512]);
        }
        #pragma unroll
        for (int i = 0; i < BN / 32; ++i) {
            const int stripe = w * (BN / 32) + i;
            const int r = stripe * 8 + srow;
            gl2lds16(Bw + (size_t)(col0 + r) * K + kt + scol, &Bs[stripe * 512]);
        }
        __syncthreads();

        #pragma unroll
        for (int kk = 0; kk < 2; ++kk) {
            const int ko = kk * 32 + (lane >> 4) * 8;
            bf16x8 afr[FM], bfr[FN];
            #pragma unroll
            for (int m = 0; m < FM; ++m)
                afr[m] = *reinterpret_cast<const bf16x8*>(
                    &As[(wr * (BM / 2) + m * 16 + (lane & 15)) * 64 + ko]);
            #pragma unroll
            for (int n = 0; n < FN; ++n)
                bfr[n] = *reinterpret_cast<const bf16x8*>(
                    &Bs[(wc * (BN / 2) + n * 16 + (lane & 15)) * 64 + ko]);
            #pragma unroll
            for (int m = 0; m < FM; ++m)
                #pragma unroll
                for (int n = 0; n < FN; ++n)
                    acc[m][n] = mfma_bf16(afr[m], bfr[n], acc[m][n]);
        }
        __syncthreads();
    }

    const int cr = (lane >> 4) * 4;
    const int cc = lane & 15;
    #pragma unroll
    for (int n = 0; n < FN; ++n) {
        const int col = col0 + wc * (BN / 2) + n * 16 + cc;
        const float bv = bias[col];
        #pragma unroll
        for (int m = 0; m < FM; ++m) {
            const int rowb = row0 + wr * (BM / 2) + m * 16 + cr;
            #pragma unroll
            for (int r = 0; r < 4; ++r)
                C[(size_t)(rowb + r) * N + col] = acc[m][n][r] + bv;
        }
    }
}

// ---------------------------------------------------------------------------
// K^T V partials per (b,h) over an s-chunk (bf16 in, fp32 accum/out).
// ---------------------------------------------------------------------------
__global__ __launch_bounds__(256) void ktv_partial(
    const unsigned short* __restrict__ Kb, const unsigned short* __restrict__ Vb,
    const int* __restrict__ mask, float* __restrict__ Mpart,
    float* __restrict__ cvpart, int S, int schunk)
{
    __shared__ float Ks[16][64];
    __shared__ float Vs[16][64];
    __shared__ float cvs[16][64];
    const int bh = blockIdx.x, chunk = blockIdx.y, BH = gridDim.x;
    const int b = bh >> 4, h = bh & 15;
    const int tid = threadIdx.x;
    const int tx = tid & 15, ty = tid >> 4;
    const int s0 = chunk * schunk;

    float acc[4][4] = {};
    float cv[4] = {0.f, 0.f, 0.f, 0.f};

    for (int sc = 0; sc < schunk; sc += 16) {
        const int s = s0 + sc + ty;
        const size_t rowoff = (size_t)(b * S + s) * DM + h * DK + tx * 4;
        const ushort4 kraw = *reinterpret_cast<const ushort4*>(Kb + rowoff);
        const ushort4 vraw = *reinterpret_cast<const ushort4*>(Vb + rowoff);
        float kv[4] = {bf2f(kraw.x), bf2f(kraw.y), bf2f(kraw.z), bf2f(kraw.w)};
        const float vv[4] = {bf2f(vraw.x), bf2f(vraw.y), bf2f(vraw.z), bf2f(vraw.w)};
        if (mask[b * S + s] == 0) {
            #pragma unroll
            for (int j = 0; j < 4; ++j) { cv[j] += vv[j]; kv[j] = 0.f; }
        }
        __syncthreads();
        #pragma unroll
        for (int j = 0; j < 4; ++j) { Ks[ty][tx * 4 + j] = kv[j]; Vs[ty][tx * 4 + j] = vv[j]; }
        __syncthreads();
        #pragma unroll
        for (int ss = 0; ss < 16; ++ss) {
            float kvv[4], vvv[4];
            #pragma unroll
            for (int i = 0; i < 4; ++i) kvv[i] = Ks[ss][ty * 4 + i];
            #pragma unroll
            for (int j = 0; j < 4; ++j) vvv[j] = Vs[ss][tx * 4 + j];
            #pragma unroll
            for (int i = 0; i < 4; ++i)
                #pragma unroll
                for (int j = 0; j < 4; ++j)
                    acc[i][j] += kvv[i] * vvv[j];
        }
    }

    const size_t mbase = ((size_t)chunk * BH + bh) * (DK * DK);
    #pragma unroll
    for (int i = 0; i < 4; ++i)
        #pragma unroll
        for (int j = 0; j < 4; ++j)
            Mpart[mbase + (size_t)(ty * 4 + i) * DK + tx * 4 + j] = acc[i][j];

    __syncthreads();
    #pragma unroll
    for (int j = 0; j < 4; ++j) cvs[ty][tx * 4 + j] = cv[j];
    __syncthreads();
    if (tid < DK) {
        float s = 0.f;
        #pragma unroll
        for (int r = 0; r < 16; ++r) s += cvs[r][tid];
        cvpart[((size_t)chunk * BH + bh) * DK + tid] = s;
    }
}

// ---------------------------------------------------------------------------
// Reduce partials: Mm[bh] = sum_c Mpart[c,bh] * (1/sqrt(DK)); cvec likewise.
// ---------------------------------------------------------------------------
__global__ __launch_bounds__(256) void reduce_m(
    const float* __restrict__ Mpart, const float* __restrict__ cvpart,
    float* __restrict__ Mm, float* __restrict__ cvec, int nchunk, int BH)
{
    const int bh = blockIdx.x;
    const int tid = threadIdx.x;
    const int e0 = blockIdx.y * 512;
    for (int e = e0 + tid; e < e0 + 512; e += 256) {
        float s = 0.f;
        for (int c = 0; c < nchunk; ++c)
            s += Mpart[((size_t)c * BH + bh) * (DK * DK) + e];
        Mm[(size_t)bh * DK * DK + e] = s * 0.125f;   // 1/sqrt(64)
    }
    if (blockIdx.y == 0 && tid < DK) {
        float s = 0.f;
        for (int c = 0; c < nchunk; ++c)
            s += cvpart[((size_t)c * BH + bh) * DK + tid];
        cvec[bh * DK + tid] = s;
    }
}

// ---------------------------------------------------------------------------
// Wf[b][o][h*64+d] = sum_e Mm[b,h,d,e] * Wo[o, h*64+e]   (bf16 out)
// ---------------------------------------------------------------------------
__device__ __forceinline__ bf16x8 ld_cvt8(const float* p) {
    const float4 x = *reinterpret_cast<const float4*>(p);
    const float4 y = *reinterpret_cast<const float4*>(p + 4);
    union { unsigned short u[8]; bf16x8 v; } r;
    r.u[0] = f2bf(x.x); r.u[1] = f2bf(x.y); r.u[2] = f2bf(x.z); r.u[3] = f2bf(x.w);
    r.u[4] = f2bf(y.x); r.u[5] = f2bf(y.y); r.u[6] = f2bf(y.z); r.u[7] = f2bf(y.w);
    return r.v;
}

__global__ __launch_bounds__(256) void fuse_w(
    const float* __restrict__ Mm, const float* __restrict__ Wo,
    unsigned short* __restrict__ Wf)
{
    const int h = blockIdx.y;
    const int b = blockIdx.z;
    const int o0 = blockIdx.x * 256;
    const int tid = threadIdx.x, lane = tid & 63, w = tid >> 6;
    const int l15 = lane & 15, q8 = (lane >> 4) * 8;
    const float* MmH = Mm + (size_t)(b * NH + h) * (DK * DK);

    f32x4 acc[4][4];
    #pragma unroll
    for (int m = 0; m < 4; ++m)
        #pragma unroll
        for (int n = 0; n < 4; ++n)
            acc[m][n] = (f32x4){0.f, 0.f, 0.f, 0.f};

    bf16x8 af[4][2], bf[4][2];
    #pragma unroll
    for (int m = 0; m < 4; ++m) {
        const int orow = o0 + w * 64 + m * 16 + l15;
        #pragma unroll
        for (int kk = 0; kk < 2; ++kk)
            af[m][kk] = ld_cvt8(Wo + (size_t)orow * DM + h * DK + kk * 32 + q8);
    }
    #pragma unroll
    for (int n = 0; n < 4; ++n) {
        const int d = n * 16 + l15;
        #pragma unroll
        for (int kk = 0; kk < 2; ++kk)
            bf[n][kk] = ld_cvt8(MmH + (size_t)d * DK + kk * 32 + q8);
    }
    #pragma unroll
    for (int kk = 0; kk < 2; ++kk)
        #pragma unroll
        for (int m = 0; m < 4; ++m)
            #pragma unroll
            for (int n = 0; n < 4; ++n)
                acc[m][n] = mfma_bf16(af[m][kk], bf[n][kk], acc[m][n]);

    const int cr = (lane >> 4) * 4, cc = lane & 15;
    #pragma unroll
    for (int n = 0; n < 4; ++n)
        #pragma unroll
        for (int m = 0; m < 4; ++m)
            #pragma unroll
            for (int r = 0; r < 4; ++r)
                Wf[(size_t)b * DM * DM +
                   (size_t)(o0 + w * 64 + m * 16 + cr + r) * DM +
                   h * DK + n * 16 + cc] = f2bf(acc[m][n][r]);
}

// ---------------------------------------------------------------------------
// bias2[b][o] = bo[o] - 1e9 * sum_j cvec[b*1024 + j] * Wo[o, j]
// ---------------------------------------------------------------------------
__global__ __launch_bounds__(256) void fuse_bias(
    const float* __restrict__ cvec, const float* __restrict__ Wo,
    const float* __restrict__ bo, float* __restrict__ bias2)
{
    const int t = blockIdx.x * 256 + threadIdx.x;   // 0..2047
    const int b = t >> 10, o = t & 1023;
    const float* cv = cvec + (b << 10);
    const float* wr = Wo + (size_t)o * DM;
    float s = 0.f;
    for (int j = 0; j < DM; j += 4) {
        const float4 c4 = *reinterpret_cast<const float4*>(cv + j);
        const float4 w4 = *reinterpret_cast<const float4*>(wr + j);
        s += c4.x * w4.x + c4.y * w4.y + c4.z * w4.z + c4.w * w4.w;
    }
    bias2[t] = bo[o] - 1.0e9f * s;
}

// ---------------------------------------------------------------------------
extern "C" void kernel_launch(void* const* d_in, const int* in_sizes, int n_in,
                              void* d_out, int out_size, void* d_ws, size_t ws_size,
                              hipStream_t stream)
{
    const float* q    = (const float*)d_in[0];
    const float* k    = (const float*)d_in[1];
    const float* v    = (const float*)d_in[2];
    const int*   mask = (const int*)  d_in[3];
    const float* Wq   = (const float*)d_in[4];
    const float* bq   = (const float*)d_in[5];
    const float* Wk   = (const float*)d_in[6];
    const float* bk   = (const float*)d_in[7];
    const float* Wv   = (const float*)d_in[8];
    const float* bv   = (const float*)d_in[9];
    const float* Wo   = (const float*)d_in[10];
    const float* bo   = (const float*)d_in[11];
    float* out = (float*)d_out;

    const int BS = in_sizes[0] / DM;   // B*S = 4096
    const int B  = 2;
    const int S  = BS / B;             // 2048
    const int BH = B * NH;             // 32
    const int SCHUNK = 64;
    const int NCHUNK = S / SCHUNK;     // 32
    const size_t BSDM = (size_t)BS * DM;   // 4M
    const size_t DMDM = (size_t)DM * DM;   // 1M

    unsigned short* ws = (unsigned short*)d_ws;
    unsigned short* qb   = ws;
    unsigned short* kb   = qb  + BSDM;
    unsigned short* vb   = kb  + BSDM;
    unsigned short* Wqb  = vb  + BSDM;
    unsigned short* Wkb  = Wqb + DMDM;
    unsigned short* Wvb  = Wkb + DMDM;
    unsigned short* Qp   = Wvb + DMDM;
    unsigned short* Kp   = Qp  + BSDM;
    unsigned short* Vp   = Kp  + BSDM;
    // aliases (dead after QKV projections):
    float* Mpart = (float*)kb;                 // 4M floats over kb+vb
    float* cvprt = (float*)Wqb;                // 64K floats
    float* Mm    = cvprt + (size_t)NCHUNK * BH * DK;       // 128K floats
    float* cvec  = Mm    + (size_t)BH * DK * DK;           // 2K floats
    unsigned short* Wf = qb;                   // 2M us (2 x 1024 x 1024 bf16)
    float* bias2 = (float*)Wkb;                // 2K floats

    const dim3 blk(256);

    // fp32 -> bf16: q,k,v (12 x 1M) + Wq,Wk,Wv (3 x 1M)
    CvtArgs cv;
    for (int i = 0; i < 4; ++i) { cv.src[0 + i] = q + (size_t)i * DMDM; cv.dst[0 + i] = qb + (size_t)i * DMDM; }
    for (int i = 0; i < 4; ++i) { cv.src[4 + i] = k + (size_t)i * DMDM; cv.dst[4 + i] = kb + (size_t)i * DMDM; }
    for (int i = 0; i < 4; ++i) { cv.src[8 + i] = v + (size_t)i * DMDM; cv.dst[8 + i] = vb + (size_t)i * DMDM; }
    cv.src[12] = Wq; cv.dst[12] = Wqb;
    cv.src[13] = Wk; cv.dst[13] = Wkb;
    cv.src[14] = Wv; cv.dst[14] = Wvb;
    cvt15<<<dim3(15 * 1024), blk, 0, stream>>>(cv);

    // batched QKV projections: 8-phase 256^2 kernel, grid (4,16,3)
    Gemm8Args ga;
    ga.A[0] = qb;  ga.A[1] = kb;  ga.A[2] = vb;
    ga.W[0] = Wqb; ga.W[1] = Wkb; ga.W[2] = Wvb;
    ga.bias[0] = bq; ga.bias[1] = bk; ga.bias[2] = bv;
    ga.C[0] = Qp;  ga.C[1] = Kp;  ga.C[2] = Vp;
    gemm8_nt_bf16<<<dim3(DM / 256, BS / 256, 3), dim3(512), 0, stream>>>(ga, BS, DM, DM);

    // per-head K^T V partials + reduction
    ktv_partial<<<dim3(BH, NCHUNK), blk, 0, stream>>>(Kp, Vp, mask, Mpart, cvprt, S, SCHUNK);
    reduce_m<<<dim3(BH, 8), blk, 0, stream>>>(Mpart, cvprt, Mm, cvec, NCHUNK, BH);

    // fold Mm into Wo (per batch) + fold mask-correction into bias
    fuse_w<<<dim3(DM / 256, NH, B), blk, 0, stream>>>(Mm, Wo, Wf);
    fuse_bias<<<dim3(B * DM / 256), blk, 0, stream>>>(cvec, Wo, bo, bias2);

    // out = Qp @ Wf[b]^T + bias2[b]  (2-phase 128x64 kernel, 512 blocks)
    gemm_nt_final<128, 64><<<dim3(DM / 64, BS / 128), blk, 0, stream>>>(
        Qp, Wf, Wf + DMDM, bias2, bias2 + DM, out, BS, DM, DM, S);
}

// Round 6
// 156.399 us; speedup vs baseline: 1.0446x; 1.0446x over previous
//
#include <hip/hip_runtime.h>
#include <stdint.h>

#define DM 1024     // D_MODEL
#define NH 16       // NUM_HEADS
#define DK 64       // D_K

typedef __attribute__((ext_vector_type(8))) __bf16 bf16x8;
typedef __attribute__((ext_vector_type(4))) float f32x4;

__device__ __forceinline__ float bf2f(unsigned short u) {
    union { uint32_t i; float f; } x; x.i = ((uint32_t)u) << 16; return x.f;
}
__device__ __forceinline__ unsigned short f2bf(float f) {
    union { float f; uint32_t i; } x; x.f = f;
    uint32_t r = x.i + 0x7fffu + ((x.i >> 16) & 1u);   // RNE
    return (unsigned short)(r >> 16);
}

__device__ __forceinline__ void gl2lds16(const void* g, void* l) {
    __builtin_amdgcn_global_load_lds(
        (const __attribute__((address_space(1))) void*)g,
        (__attribute__((address_space(3))) void*)l, 16, 0, 0);
}

__device__ __forceinline__ f32x4 mfma_bf16(bf16x8 a, bf16x8 b, f32x4 c) {
    return __builtin_amdgcn_mfma_f32_16x16x32_bf16(a, b, c, 0, 0, 0);
}

template<int N> __device__ __forceinline__ void waitvm() {
    if constexpr (N == 4)      asm volatile("s_waitcnt vmcnt(4)" ::: "memory");
    else if constexpr (N == 2) asm volatile("s_waitcnt vmcnt(2)" ::: "memory");
    else if constexpr (N == 0) asm volatile("s_waitcnt vmcnt(0)" ::: "memory");
}

// ---------------------------------------------------------------------------
// fp32 -> bf16 conversion, 15 segments of exactly 1M floats (2^18 float4).
// ---------------------------------------------------------------------------
struct CvtArgs {
    const float* src[15];
    unsigned short* dst[15];
};

__global__ __launch_bounds__(256) void cvt15(CvtArgs a) {
    const int t = blockIdx.x * 256 + threadIdx.x;
    const int seg = t >> 18;
    const int off = t & 0x3ffff;
    const float4 v = reinterpret_cast<const float4*>(a.src[seg])[off];
    ushort4 o;
    o.x = f2bf(v.x); o.y = f2bf(v.y); o.z = f2bf(v.z); o.w = f2bf(v.w);
    reinterpret_cast<ushort4*>(a.dst[seg])[off] = o;
}

// ---------------------------------------------------------------------------
// Unified NT GEMM: C[z][M,N] = A[z] @ W[z]^T + bias[z]
// 128x128 tile, BK=32, 8 waves (2Mx4N, per-wave 64x32), 4-deep LDS ring
// (4 x 16KB = 64KB -> 2 blocks/CU resident), stage 3 tiles ahead via
// global_load_lds, one vmcnt(2) + one s_barrier per K-tile.
// Per-row W/bias split (rowSplit) supports the per-batch final projection.
// XCD-aware block swizzle on flattened grid (nwg % 8 == 0).
// bf16 output goes through an LDS-staged coalesced epilogue; fp32 direct.
// LDS swizzle pair (proven round 5): write side = lane-permuted global src
// (tid^((tid>>4)&3)), read side = byte-offset XOR (l15&12)<<2.
// ---------------------------------------------------------------------------
template<typename OutT>
struct GKArgs {
    const unsigned short* A[3];
    const unsigned short* Wlo[3];
    const unsigned short* Whi[3];
    const float* blo[3];
    const float* bhi[3];
    OutT* C[3];
};

template<typename OutT>
__global__ __launch_bounds__(512, 4) void gemmk(GKArgs<OutT> g, int M, int N, int K,
                                               int nwgx, int rowSplit)
{
    const int z = blockIdx.y;
    const int nwg = gridDim.x;
    const int f = blockIdx.x;
    const int q = nwg >> 3;                       // nwg % 8 == 0
    const int f2 = (f & 7) * q + (f >> 3);        // XCD-contiguous chunks
    const int bx = f2 % nwgx, by = f2 / nwgx;
    const int row0 = by * 128, col0 = bx * 128;

    const unsigned short* __restrict__ A = g.A[z];
    const bool hi = row0 >= rowSplit;
    const unsigned short* __restrict__ Bw = hi ? g.Whi[z] : g.Wlo[z];
    const float* __restrict__ bias = hi ? g.bhi[z] : g.blo[z];
    OutT* __restrict__ C = g.C[z];

    __shared__ unsigned short lds[4][2][4096];    // [buf][A|B][128 rows * 32 k]

    const int tid  = threadIdx.x;
    const int lane = tid & 63;
    const int w    = tid >> 6;          // wave 0..7
    const int wr   = w >> 2, wc = w & 3;
    const int l15  = lane & 15;
    const int swz  = (l15 & 12) << 2;   // read-side byte XOR (bits 4-5)

    // write-side: lane-permuted global source, linear LDS dest
    const int tidp = tid ^ ((tid >> 4) & 3);
    const unsigned short* aSrc = A  + (size_t)(row0 + (tidp >> 2)) * K + (tidp & 3) * 8;
    const unsigned short* bSrc = Bw + (size_t)(col0 + (tidp >> 2)) * K + (tidp & 3) * 8;

    const int aBase = (((wr * 64 + l15) * 64) + (lane >> 4) * 16) ^ swz;  // + m*1024
    const int bBase = (((wc * 32 + l15) * 64) + (lane >> 4) * 16) ^ swz;  // + n*1024

    f32x4 acc[4][2];
    #pragma unroll
    for (int m = 0; m < 4; ++m)
        #pragma unroll
        for (int n = 0; n < 2; ++n)
            acc[m][n] = (f32x4){0.f, 0.f, 0.f, 0.f};

    const int NT = K >> 5;   // 32 tiles for K=1024

    #define STAGE(t) do { \
        gl2lds16(aSrc + (size_t)(t) * 32, &lds[(t) & 3][0][(size_t)tid * 8]); \
        gl2lds16(bSrc + (size_t)(t) * 32, &lds[(t) & 3][1][(size_t)tid * 8]); \
    } while (0)

    // prologue: stage tiles 0,1,2; wait for tile 0 (drain to 4 of 6)
    STAGE(0); STAGE(1); STAGE(2);
    waitvm<4>();
    __builtin_amdgcn_s_barrier();

    #pragma unroll 4
    for (int t = 0; t < NT; ++t) {
        if (t + 3 < NT) STAGE(t + 3);
        const char* LA = (const char*)&lds[t & 3][0][0];
        const char* LB = (const char*)&lds[t & 3][1][0];
        bf16x8 af[4], bf[2];
        #pragma unroll
        for (int m = 0; m < 4; ++m)
            af[m] = *reinterpret_cast<const bf16x8*>(LA + m * 1024 + aBase);
        #pragma unroll
        for (int n = 0; n < 2; ++n)
            bf[n] = *reinterpret_cast<const bf16x8*>(LB + n * 1024 + bBase);
        __builtin_amdgcn_s_setprio(1);
        #pragma unroll
        for (int m = 0; m < 4; ++m)
            #pragma unroll
            for (int n = 0; n < 2; ++n)
                acc[m][n] = mfma_bf16(af[m], bf[n], acc[m][n]);
        __builtin_amdgcn_s_setprio(0);
        // vmcnt chain: tile tau's stages complete by tau+1's vmcnt(2);
        // buffer for tau+3 therefore ready 2 tiles before first read.
        if (t == NT - 3)      waitvm<0>();   // tail: drain everything
        else if (t + 3 < NT)  waitvm<2>();
        __builtin_amdgcn_s_barrier();
    }
    #undef STAGE

    // ---- epilogue: C/D layout col=lane&15, row=(lane>>4)*4+reg
    const int cr = (lane >> 4) * 4, cc = l15;
    if constexpr (sizeof(OutT) == 2) {
        // LDS-staged coalesced bf16 store (fixes half-line write amplification)
        unsigned short* CE = &lds[0][0][0];        // 32KB: [128 rows][128 cols]
        #pragma unroll
        for (int n = 0; n < 2; ++n) {
            const int col = wc * 32 + n * 16 + cc;
            const float bv = bias[col0 + col];
            #pragma unroll
            for (int m = 0; m < 4; ++m) {
                const int rowb = wr * 64 + m * 16 + cr;
                #pragma unroll
                for (int r = 0; r < 4; ++r)
                    CE[(rowb + r) * 128 + col] = f2bf(acc[m][n][r] + bv);
            }
        }
        __syncthreads();
        #pragma unroll
        for (int j = 0; j < 4; ++j) {
            const int off = j * 8192 + tid * 16;   // byte offset, 256B per row
            const int row = off >> 8;
            const int cole = (off & 255) >> 1;
            *reinterpret_cast<uint4*>(&C[(size_t)(row0 + row) * N + col0 + cole]) =
                *reinterpret_cast<const uint4*>((const char*)CE + off);
        }
    } else {
        #pragma unroll
        for (int n = 0; n < 2; ++n) {
            const int col = col0 + wc * 32 + n * 16 + cc;
            const float bv = bias[col];
            #pragma unroll
            for (int m = 0; m < 4; ++m) {
                const int rowb = row0 + wr * 64 + m * 16 + cr;
                #pragma unroll
                for (int r = 0; r < 4; ++r)
                    C[(size_t)(rowb + r) * N + col] = acc[m][n][r] + bv;
            }
        }
    }
}

// ---------------------------------------------------------------------------
// K^T V partials per (b,h) over an s-chunk (bf16 in, fp32 accum/out).
// ---------------------------------------------------------------------------
__global__ __launch_bounds__(256) void ktv_partial(
    const unsigned short* __restrict__ Kb, const unsigned short* __restrict__ Vb,
    const int* __restrict__ mask, float* __restrict__ Mpart,
    float* __restrict__ cvpart, int S, int schunk)
{
    __shared__ float Ks[16][64];
    __shared__ float Vs[16][64];
    __shared__ float cvs[16][64];
    const int bh = blockIdx.x, chunk = blockIdx.y, BH = gridDim.x;
    const int b = bh >> 4, h = bh & 15;
    const int tid = threadIdx.x;
    const int tx = tid & 15, ty = tid >> 4;
    const int s0 = chunk * schunk;

    float acc[4][4] = {};
    float cv[4] = {0.f, 0.f, 0.f, 0.f};

    for (int sc = 0; sc < schunk; sc += 16) {
        const int s = s0 + sc + ty;
        const size_t rowoff = (size_t)(b * S + s) * DM + h * DK + tx * 4;
        const ushort4 kraw = *reinterpret_cast<const ushort4*>(Kb + rowoff);
        const ushort4 vraw = *reinterpret_cast<const ushort4*>(Vb + rowoff);
        float kv[4] = {bf2f(kraw.x), bf2f(kraw.y), bf2f(kraw.z), bf2f(kraw.w)};
        const float vv[4] = {bf2f(vraw.x), bf2f(vraw.y), bf2f(vraw.z), bf2f(vraw.w)};
        if (mask[b * S + s] == 0) {
            #pragma unroll
            for (int j = 0; j < 4; ++j) { cv[j] += vv[j]; kv[j] = 0.f; }
        }
        __syncthreads();
        #pragma unroll
        for (int j = 0; j < 4; ++j) { Ks[ty][tx * 4 + j] = kv[j]; Vs[ty][tx * 4 + j] = vv[j]; }
        __syncthreads();
        #pragma unroll
        for (int ss = 0; ss < 16; ++ss) {
            float kvv[4], vvv[4];
            #pragma unroll
            for (int i = 0; i < 4; ++i) kvv[i] = Ks[ss][ty * 4 + i];
            #pragma unroll
            for (int j = 0; j < 4; ++j) vvv[j] = Vs[ss][tx * 4 + j];
            #pragma unroll
            for (int i = 0; i < 4; ++i)
                #pragma unroll
                for (int j = 0; j < 4; ++j)
                    acc[i][j] += kvv[i] * vvv[j];
        }
    }

    const size_t mbase = ((size_t)chunk * BH + bh) * (DK * DK);
    #pragma unroll
    for (int i = 0; i < 4; ++i)
        #pragma unroll
        for (int j = 0; j < 4; ++j)
            Mpart[mbase + (size_t)(ty * 4 + i) * DK + tx * 4 + j] = acc[i][j];

    __syncthreads();
    #pragma unroll
    for (int j = 0; j < 4; ++j) cvs[ty][tx * 4 + j] = cv[j];
    __syncthreads();
    if (tid < DK) {
        float s = 0.f;
        #pragma unroll
        for (int r = 0; r < 16; ++r) s += cvs[r][tid];
        cvpart[((size_t)chunk * BH + bh) * DK + tid] = s;
    }
}

// ---------------------------------------------------------------------------
// Reduce partials: Mm[bh] = sum_c Mpart[c,bh] * (1/sqrt(DK)); cvec likewise.
// ---------------------------------------------------------------------------
__global__ __launch_bounds__(256) void reduce_m(
    const float* __restrict__ Mpart, const float* __restrict__ cvpart,
    float* __restrict__ Mm, float* __restrict__ cvec, int nchunk, int BH)
{
    const int bh = blockIdx.x;
    const int tid = threadIdx.x;
    const int e0 = blockIdx.y * 512;
    for (int e = e0 + tid; e < e0 + 512; e += 256) {
        float s = 0.f;
        for (int c = 0; c < nchunk; ++c)
            s += Mpart[((size_t)c * BH + bh) * (DK * DK) + e];
        Mm[(size_t)bh * DK * DK + e] = s * 0.125f;   // 1/sqrt(64)
    }
    if (blockIdx.y == 0 && tid < DK) {
        float s = 0.f;
        for (int c = 0; c < nchunk; ++c)
            s += cvpart[((size_t)c * BH + bh) * DK + tid];
        cvec[bh * DK + tid] = s;
    }
}

// ---------------------------------------------------------------------------
// Wf[b][o][h*64+d] = sum_e Mm[b,h,d,e] * Wo[o, h*64+e]   (bf16 out)
// ---------------------------------------------------------------------------
__device__ __forceinline__ bf16x8 ld_cvt8(const float* p) {
    const float4 x = *reinterpret_cast<const float4*>(p);
    const float4 y = *reinterpret_cast<const float4*>(p + 4);
    union { unsigned short u[8]; bf16x8 v; } r;
    r.u[0] = f2bf(x.x); r.u[1] = f2bf(x.y); r.u[2] = f2bf(x.z); r.u[3] = f2bf(x.w);
    r.u[4] = f2bf(y.x); r.u[5] = f2bf(y.y); r.u[6] = f2bf(y.z); r.u[7] = f2bf(y.w);
    return r.v;
}

__global__ __launch_bounds__(256) void fuse_w(
    const float* __restrict__ Mm, const float* __restrict__ Wo,
    unsigned short* __restrict__ Wf)
{
    const int h = blockIdx.y;
    const int b = blockIdx.z;
    const int o0 = blockIdx.x * 256;
    const int tid = threadIdx.x, lane = tid & 63, w = tid >> 6;
    const int l15 = lane & 15, q8 = (lane >> 4) * 8;
    const float* MmH = Mm + (size_t)(b * NH + h) * (DK * DK);

    f32x4 acc[4][4];
    #pragma unroll
    for (int m = 0; m < 4; ++m)
        #pragma unroll
        for (int n = 0; n < 4; ++n)
            acc[m][n] = (f32x4){0.f, 0.f, 0.f, 0.f};

    bf16x8 af[4][2], bf[4][2];
    #pragma unroll
    for (int m = 0; m < 4; ++m) {
        const int orow = o0 + w * 64 + m * 16 + l15;
        #pragma unroll
        for (int kk = 0; kk < 2; ++kk)
            af[m][kk] = ld_cvt8(Wo + (size_t)orow * DM + h * DK + kk * 32 + q8);
    }
    #pragma unroll
    for (int n = 0; n < 4; ++n) {
        const int d = n * 16 + l15;
        #pragma unroll
        for (int kk = 0; kk < 2; ++kk)
            bf[n][kk] = ld_cvt8(MmH + (size_t)d * DK + kk * 32 + q8);
    }
    #pragma unroll
    for (int kk = 0; kk < 2; ++kk)
        #pragma unroll
        for (int m = 0; m < 4; ++m)
            #pragma unroll
            for (int n = 0; n < 4; ++n)
                acc[m][n] = mfma_bf16(af[m][kk], bf[n][kk], acc[m][n]);

    const int cr = (lane >> 4) * 4, cc = lane & 15;
    #pragma unroll
    for (int n = 0; n < 4; ++n)
        #pragma unroll
        for (int m = 0; m < 4; ++m)
            #pragma unroll
            for (int r = 0; r < 4; ++r)
                Wf[(size_t)b * DM * DM +
                   (size_t)(o0 + w * 64 + m * 16 + cr + r) * DM +
                   h * DK + n * 16 + cc] = f2bf(acc[m][n][r]);
}

// ---------------------------------------------------------------------------
// bias2[b][o] = bo[o] - 1e9 * sum_j cvec[b*1024 + j] * Wo[o, j]
// ---------------------------------------------------------------------------
__global__ __launch_bounds__(256) void fuse_bias(
    const float* __restrict__ cvec, const float* __restrict__ Wo,
    const float* __restrict__ bo, float* __restrict__ bias2)
{
    const int t = blockIdx.x * 256 + threadIdx.x;   // 0..2047
    const int b = t >> 10, o = t & 1023;
    const float* cv = cvec + (b << 10);
    const float* wr = Wo + (size_t)o * DM;
    float s = 0.f;
    for (int j = 0; j < DM; j += 4) {
        const float4 c4 = *reinterpret_cast<const float4*>(cv + j);
        const float4 w4 = *reinterpret_cast<const float4*>(wr + j);
        s += c4.x * w4.x + c4.y * w4.y + c4.z * w4.z + c4.w * w4.w;
    }
    bias2[t] = bo[o] - 1.0e9f * s;
}

// ---------------------------------------------------------------------------
extern "C" void kernel_launch(void* const* d_in, const int* in_sizes, int n_in,
                              void* d_out, int out_size, void* d_ws, size_t ws_size,
                              hipStream_t stream)
{
    const float* q    = (const float*)d_in[0];
    const float* k    = (const float*)d_in[1];
    const float* v    = (const float*)d_in[2];
    const int*   mask = (const int*)  d_in[3];
    const float* Wq   = (const float*)d_in[4];
    const float* bq   = (const float*)d_in[5];
    const float* Wk   = (const float*)d_in[6];
    const float* bk   = (const float*)d_in[7];
    const float* Wv   = (const float*)d_in[8];
    const float* bv   = (const float*)d_in[9];
    const float* Wo   = (const float*)d_in[10];
    const float* bo   = (const float*)d_in[11];
    float* out = (float*)d_out;

    const int BS = in_sizes[0] / DM;   // B*S = 4096
    const int B  = 2;
    const int S  = BS / B;             // 2048
    const int BH = B * NH;             // 32
    const int SCHUNK = 64;
    const int NCHUNK = S / SCHUNK;     // 32
    const size_t BSDM = (size_t)BS * DM;   // 4M
    const size_t DMDM = (size_t)DM * DM;   // 1M

    unsigned short* ws = (unsigned short*)d_ws;
    unsigned short* qb   = ws;
    unsigned short* kb   = qb  + BSDM;
    unsigned short* vb   = kb  + BSDM;
    unsigned short* Wqb  = vb  + BSDM;
    unsigned short* Wkb  = Wqb + DMDM;
    unsigned short* Wvb  = Wkb + DMDM;
    unsigned short* Qp   = Wvb + DMDM;
    unsigned short* Kp   = Qp  + BSDM;
    unsigned short* Vp   = Kp  + BSDM;
    // aliases (dead after QKV projections):
    float* Mpart = (float*)kb;                 // 4M floats over kb+vb
    float* cvprt = (float*)Wqb;                // 64K floats
    float* Mm    = cvprt + (size_t)NCHUNK * BH * DK;       // 128K floats
    float* cvec  = Mm    + (size_t)BH * DK * DK;           // 2K floats
    unsigned short* Wf = qb;                   // 2M us (2 x 1024 x 1024 bf16)
    float* bias2 = (float*)Wkb;                // 2K floats

    const dim3 blk(256);

    // fp32 -> bf16: q,k,v (12 x 1M) + Wq,Wk,Wv (3 x 1M)
    CvtArgs cv;
    for (int i = 0; i < 4; ++i) { cv.src[0 + i] = q + (size_t)i * DMDM; cv.dst[0 + i] = qb + (size_t)i * DMDM; }
    for (int i = 0; i < 4; ++i) { cv.src[4 + i] = k + (size_t)i * DMDM; cv.dst[4 + i] = kb + (size_t)i * DMDM; }
    for (int i = 0; i < 4; ++i) { cv.src[8 + i] = v + (size_t)i * DMDM; cv.dst[8 + i] = vb + (size_t)i * DMDM; }
    cv.src[12] = Wq; cv.dst[12] = Wqb;
    cv.src[13] = Wk; cv.dst[13] = Wkb;
    cv.src[14] = Wv; cv.dst[14] = Wvb;
    cvt15<<<dim3(15 * 1024), blk, 0, stream>>>(cv);

    // batched QKV projections: 128^2-tile ring kernel, grid (256, 3) = 768 blocks
    GKArgs<unsigned short> ga;
    ga.A[0] = qb;  ga.A[1] = kb;  ga.A[2] = vb;
    ga.Wlo[0] = ga.Whi[0] = Wqb;
    ga.Wlo[1] = ga.Whi[1] = Wkb;
    ga.Wlo[2] = ga.Whi[2] = Wvb;
    ga.blo[0] = ga.bhi[0] = bq;
    ga.blo[1] = ga.bhi[1] = bk;
    ga.blo[2] = ga.bhi[2] = bv;
    ga.C[0] = Qp;  ga.C[1] = Kp;  ga.C[2] = Vp;
    gemmk<unsigned short><<<dim3((DM / 128) * (BS / 128), 3), dim3(512), 0, stream>>>(
        ga, BS, DM, DM, DM / 128, 1 << 30);

    // per-head K^T V partials + reduction
    ktv_partial<<<dim3(BH, NCHUNK), blk, 0, stream>>>(Kp, Vp, mask, Mpart, cvprt, S, SCHUNK);
    reduce_m<<<dim3(BH, 8), blk, 0, stream>>>(Mpart, cvprt, Mm, cvec, NCHUNK, BH);

    // fold Mm into Wo (per batch) + fold mask-correction into bias
    fuse_w<<<dim3(DM / 256, NH, B), blk, 0, stream>>>(Mm, Wo, Wf);
    fuse_bias<<<dim3(B * DM / 256), blk, 0, stream>>>(cvec, Wo, bo, bias2);

    // out = Qp @ Wf[b]^T + bias2[b]: same kernel, grid (256, 1), row-split at S
    GKArgs<float> gf;
    gf.A[0] = Qp;
    gf.Wlo[0] = Wf;        gf.Whi[0] = Wf + DMDM;
    gf.blo[0] = bias2;     gf.bhi[0] = bias2 + DM;
    gf.C[0] = out;
    gf.A[1] = gf.A[2] = nullptr;
    gf.Wlo[1] = gf.Wlo[2] = gf.Whi[1] = gf.Whi[2] = nullptr;
    gf.blo[1] = gf.blo[2] = gf.bhi[1] = gf.bhi[2] = nullptr;
    gf.C[1] = gf.C[2] = nullptr;
    gemmk<float><<<dim3((DM / 128) * (BS / 128), 1), dim3(512), 0, stream>>>(
        gf, BS, DM, DM, DM / 128, S);
}

// Round 7
// 119.879 us; speedup vs baseline: 1.3629x; 1.3046x over previous
//
#include <hip/hip_runtime.h>
#include <stdint.h>

#define DM 1024     // D_MODEL
#define NH 16       // NUM_HEADS
#define DK 64       // D_K

typedef __attribute__((ext_vector_type(8))) __bf16 bf16x8;
typedef __attribute__((ext_vector_type(4))) float f32x4;

__device__ __forceinline__ float bf2f(unsigned short u) {
    union { uint32_t i; float f; } x; x.i = ((uint32_t)u) << 16; return x.f;
}
__device__ __forceinline__ unsigned short f2bf(float f) {
    union { float f; uint32_t i; } x; x.f = f;
    uint32_t r = x.i + 0x7fffu + ((x.i >> 16) & 1u);   // RNE
    return (unsigned short)(r >> 16);
}

__device__ __forceinline__ void gl2lds16(const void* g, void* l) {
    __builtin_amdgcn_global_load_lds(
        (const __attribute__((address_space(1))) void*)g,
        (__attribute__((address_space(3))) void*)l, 16, 0, 0);
}

__device__ __forceinline__ f32x4 mfma_bf16(bf16x8 a, bf16x8 b, f32x4 c) {
    return __builtin_amdgcn_mfma_f32_16x16x32_bf16(a, b, c, 0, 0, 0);
}

template<int N> __device__ __forceinline__ void waitvm() {
    if constexpr (N == 4)      asm volatile("s_waitcnt vmcnt(4)" ::: "memory");
    else if constexpr (N == 2) asm volatile("s_waitcnt vmcnt(2)" ::: "memory");
    else if constexpr (N == 0) asm volatile("s_waitcnt vmcnt(0)" ::: "memory");
}

// ---------------------------------------------------------------------------
// fp32 -> bf16 conversion, 15 segments of exactly 1M floats (2^18 float4).
// ---------------------------------------------------------------------------
struct CvtArgs {
    const float* src[15];
    unsigned short* dst[15];
};

__global__ __launch_bounds__(256) void cvt15(CvtArgs a) {
    const int t = blockIdx.x * 256 + threadIdx.x;
    const int seg = t >> 18;
    const int off = t & 0x3ffff;
    const float4 v = reinterpret_cast<const float4*>(a.src[seg])[off];
    ushort4 o;
    o.x = f2bf(v.x); o.y = f2bf(v.y); o.z = f2bf(v.z); o.w = f2bf(v.w);
    reinterpret_cast<ushort4*>(a.dst[seg])[off] = o;
}

// ---------------------------------------------------------------------------
// Unified NT GEMM: C[z][M,N] = A[z] @ W[z]^T + bias[z]
// 128x128 tile, BK=32, 8 waves (2Mx4N, per-wave 64x32), 4-deep LDS ring
// (4 x 16KB = 64KB -> 2 blocks/CU resident), stage 3 tiles ahead via
// global_load_lds, one vmcnt(2) + one s_barrier per K-tile.
// Per-row W/bias split (rowSplit) supports the per-batch final projection.
// XCD-aware block swizzle on flattened grid (nwg % 8 == 0).
// bf16 output goes through an LDS-staged coalesced epilogue; fp32 direct.
// ---------------------------------------------------------------------------
template<typename OutT>
struct GKArgs {
    const unsigned short* A[3];
    const unsigned short* Wlo[3];
    const unsigned short* Whi[3];
    const float* blo[3];
    const float* bhi[3];
    OutT* C[3];
};

template<typename OutT>
__global__ __launch_bounds__(512, 4) void gemmk(GKArgs<OutT> g, int M, int N, int K,
                                               int nwgx, int rowSplit)
{
    const int z = blockIdx.y;
    const int nwg = gridDim.x;
    const int f = blockIdx.x;
    const int q = nwg >> 3;                       // nwg % 8 == 0
    const int f2 = (f & 7) * q + (f >> 3);        // XCD-contiguous chunks
    const int bx = f2 % nwgx, by = f2 / nwgx;
    const int row0 = by * 128, col0 = bx * 128;

    const unsigned short* __restrict__ A = g.A[z];
    const bool hi = row0 >= rowSplit;
    const unsigned short* __restrict__ Bw = hi ? g.Whi[z] : g.Wlo[z];
    const float* __restrict__ bias = hi ? g.bhi[z] : g.blo[z];
    OutT* __restrict__ C = g.C[z];

    __shared__ unsigned short lds[4][2][4096];    // [buf][A|B][128 rows * 32 k]

    const int tid  = threadIdx.x;
    const int lane = tid & 63;
    const int w    = tid >> 6;          // wave 0..7
    const int wr   = w >> 2, wc = w & 3;
    const int l15  = lane & 15;
    const int swz  = (l15 & 12) << 2;   // read-side byte XOR (bits 4-5)

    // write-side: lane-permuted global source, linear LDS dest
    const int tidp = tid ^ ((tid >> 4) & 3);
    const unsigned short* aSrc = A  + (size_t)(row0 + (tidp >> 2)) * K + (tidp & 3) * 8;
    const unsigned short* bSrc = Bw + (size_t)(col0 + (tidp >> 2)) * K + (tidp & 3) * 8;

    const int aBase = (((wr * 64 + l15) * 64) + (lane >> 4) * 16) ^ swz;  // + m*1024
    const int bBase = (((wc * 32 + l15) * 64) + (lane >> 4) * 16) ^ swz;  // + n*1024

    f32x4 acc[4][2];
    #pragma unroll
    for (int m = 0; m < 4; ++m)
        #pragma unroll
        for (int n = 0; n < 2; ++n)
            acc[m][n] = (f32x4){0.f, 0.f, 0.f, 0.f};

    const int NT = K >> 5;   // 32 tiles for K=1024

    #define STAGE(t) do { \
        gl2lds16(aSrc + (size_t)(t) * 32, &lds[(t) & 3][0][(size_t)tid * 8]); \
        gl2lds16(bSrc + (size_t)(t) * 32, &lds[(t) & 3][1][(size_t)tid * 8]); \
    } while (0)

    // prologue: stage tiles 0,1,2; wait for tile 0 (drain to 4 of 6)
    STAGE(0); STAGE(1); STAGE(2);
    waitvm<4>();
    __builtin_amdgcn_s_barrier();

    #pragma unroll 4
    for (int t = 0; t < NT; ++t) {
        if (t + 3 < NT) STAGE(t + 3);
        const char* LA = (const char*)&lds[t & 3][0][0];
        const char* LB = (const char*)&lds[t & 3][1][0];
        bf16x8 af[4], bf[2];
        #pragma unroll
        for (int m = 0; m < 4; ++m)
            af[m] = *reinterpret_cast<const bf16x8*>(LA + m * 1024 + aBase);
        #pragma unroll
        for (int n = 0; n < 2; ++n)
            bf[n] = *reinterpret_cast<const bf16x8*>(LB + n * 1024 + bBase);
        __builtin_amdgcn_s_setprio(1);
        #pragma unroll
        for (int m = 0; m < 4; ++m)
            #pragma unroll
            for (int n = 0; n < 2; ++n)
                acc[m][n] = mfma_bf16(af[m], bf[n], acc[m][n]);
        __builtin_amdgcn_s_setprio(0);
        // vmcnt chain: tile tau's stages complete by tau+1's vmcnt(2);
        // buffer for tau+3 therefore ready 2 tiles before first read.
        if (t == NT - 3)      waitvm<0>();   // tail: drain everything
        else if (t + 3 < NT)  waitvm<2>();
        __builtin_amdgcn_s_barrier();
    }
    #undef STAGE

    // ---- epilogue: C/D layout col=lane&15, row=(lane>>4)*4+reg
    const int cr = (lane >> 4) * 4, cc = l15;
    if constexpr (sizeof(OutT) == 2) {
        // LDS-staged coalesced bf16 store (fixes half-line write amplification)
        unsigned short* CE = &lds[0][0][0];        // 32KB: [128 rows][128 cols]
        #pragma unroll
        for (int n = 0; n < 2; ++n) {
            const int col = wc * 32 + n * 16 + cc;
            const float bv = bias[col0 + col];
            #pragma unroll
            for (int m = 0; m < 4; ++m) {
                const int rowb = wr * 64 + m * 16 + cr;
                #pragma unroll
                for (int r = 0; r < 4; ++r)
                    CE[(rowb + r) * 128 + col] = f2bf(acc[m][n][r] + bv);
            }
        }
        __syncthreads();
        #pragma unroll
        for (int j = 0; j < 4; ++j) {
            const int off = j * 8192 + tid * 16;   // byte offset, 256B per row
            const int row = off >> 8;
            const int cole = (off & 255) >> 1;
            *reinterpret_cast<uint4*>(&C[(size_t)(row0 + row) * N + col0 + cole]) =
                *reinterpret_cast<const uint4*>((const char*)CE + off);
        }
    } else {
        #pragma unroll
        for (int n = 0; n < 2; ++n) {
            const int col = col0 + wc * 32 + n * 16 + cc;
            const float bv = bias[col];
            #pragma unroll
            for (int m = 0; m < 4; ++m) {
                const int rowb = row0 + wr * 64 + m * 16 + cr;
                #pragma unroll
                for (int r = 0; r < 4; ++r)
                    C[(size_t)(rowb + r) * N + col] = acc[m][n][r] + bv;
            }
        }
    }
}

// ---------------------------------------------------------------------------
// K^T V partials per (b,h) over an s-chunk (bf16 in, fp32 accum/out).
// ---------------------------------------------------------------------------
__global__ __launch_bounds__(256) void ktv_partial(
    const unsigned short* __restrict__ Kb, const unsigned short* __restrict__ Vb,
    const int* __restrict__ mask, float* __restrict__ Mpart,
    float* __restrict__ cvpart, int S, int schunk)
{
    __shared__ float Ks[16][64];
    __shared__ float Vs[16][64];
    __shared__ float cvs[16][64];
    const int bh = blockIdx.x, chunk = blockIdx.y, BH = gridDim.x;
    const int b = bh >> 4, h = bh & 15;
    const int tid = threadIdx.x;
    const int tx = tid & 15, ty = tid >> 4;
    const int s0 = chunk * schunk;

    float acc[4][4] = {};
    float cv[4] = {0.f, 0.f, 0.f, 0.f};

    for (int sc = 0; sc < schunk; sc += 16) {
        const int s = s0 + sc + ty;
        const size_t rowoff = (size_t)(b * S + s) * DM + h * DK + tx * 4;
        const ushort4 kraw = *reinterpret_cast<const ushort4*>(Kb + rowoff);
        const ushort4 vraw = *reinterpret_cast<const ushort4*>(Vb + rowoff);
        float kv[4] = {bf2f(kraw.x), bf2f(kraw.y), bf2f(kraw.z), bf2f(kraw.w)};
        const float vv[4] = {bf2f(vraw.x), bf2f(vraw.y), bf2f(vraw.z), bf2f(vraw.w)};
        if (mask[b * S + s] == 0) {
            #pragma unroll
            for (int j = 0; j < 4; ++j) { cv[j] += vv[j]; kv[j] = 0.f; }
        }
        __syncthreads();
        #pragma unroll
        for (int j = 0; j < 4; ++j) { Ks[ty][tx * 4 + j] = kv[j]; Vs[ty][tx * 4 + j] = vv[j]; }
        __syncthreads();
        #pragma unroll
        for (int ss = 0; ss < 16; ++ss) {
            float kvv[4], vvv[4];
            #pragma unroll
            for (int i = 0; i < 4; ++i) kvv[i] = Ks[ss][ty * 4 + i];
            #pragma unroll
            for (int j = 0; j < 4; ++j) vvv[j] = Vs[ss][tx * 4 + j];
            #pragma unroll
            for (int i = 0; i < 4; ++i)
                #pragma unroll
                for (int j = 0; j < 4; ++j)
                    acc[i][j] += kvv[i] * vvv[j];
        }
    }

    const size_t mbase = ((size_t)chunk * BH + bh) * (DK * DK);
    #pragma unroll
    for (int i = 0; i < 4; ++i)
        #pragma unroll
        for (int j = 0; j < 4; ++j)
            Mpart[mbase + (size_t)(ty * 4 + i) * DK + tx * 4 + j] = acc[i][j];

    __syncthreads();
    #pragma unroll
    for (int j = 0; j < 4; ++j) cvs[ty][tx * 4 + j] = cv[j];
    __syncthreads();
    if (tid < DK) {
        float s = 0.f;
        #pragma unroll
        for (int r = 0; r < 16; ++r) s += cvs[r][tid];
        cvpart[((size_t)chunk * BH + bh) * DK + tid] = s;
    }
}

// ---------------------------------------------------------------------------
// Reduce partials: Mm[bh] = sum_c Mpart[c,bh] * (1/sqrt(DK)); cvec likewise.
// ---------------------------------------------------------------------------
__global__ __launch_bounds__(256) void reduce_m(
    const float* __restrict__ Mpart, const float* __restrict__ cvpart,
    float* __restrict__ Mm, float* __restrict__ cvec, int nchunk, int BH)
{
    const int bh = blockIdx.x;
    const int tid = threadIdx.x;
    const int e0 = blockIdx.y * 512;
    for (int e = e0 + tid; e < e0 + 512; e += 256) {
        float s = 0.f;
        for (int c = 0; c < nchunk; ++c)
            s += Mpart[((size_t)c * BH + bh) * (DK * DK) + e];
        Mm[(size_t)bh * DK * DK + e] = s * 0.125f;   // 1/sqrt(64)
    }
    if (blockIdx.y == 0 && tid < DK) {
        float s = 0.f;
        for (int c = 0; c < nchunk; ++c)
            s += cvpart[((size_t)c * BH + bh) * DK + tid];
        cvec[bh * DK + tid] = s;
    }
}

// ---------------------------------------------------------------------------
// Wf[b][o][h*64+d] = sum_e Mm[b,h,d,e] * Wo[o, h*64+e]   (bf16 out)
// ---------------------------------------------------------------------------
__device__ __forceinline__ bf16x8 ld_cvt8(const float* p) {
    const float4 x = *reinterpret_cast<const float4*>(p);
    const float4 y = *reinterpret_cast<const float4*>(p + 4);
    union { unsigned short u[8]; bf16x8 v; } r;
    r.u[0] = f2bf(x.x); r.u[1] = f2bf(x.y); r.u[2] = f2bf(x.z); r.u[3] = f2bf(x.w);
    r.u[4] = f2bf(y.x); r.u[5] = f2bf(y.y); r.u[6] = f2bf(y.z); r.u[7] = f2bf(y.w);
    return r.v;
}

__global__ __launch_bounds__(256) void fuse_w(
    const float* __restrict__ Mm, const float* __restrict__ Wo,
    unsigned short* __restrict__ Wf)
{
    const int h = blockIdx.y;
    const int b = blockIdx.z;
    const int o0 = blockIdx.x * 256;
    const int tid = threadIdx.x, lane = tid & 63, w = tid >> 6;
    const int l15 = lane & 15, q8 = (lane >> 4) * 8;
    const float* MmH = Mm + (size_t)(b * NH + h) * (DK * DK);

    f32x4 acc[4][4];
    #pragma unroll
    for (int m = 0; m < 4; ++m)
        #pragma unroll
        for (int n = 0; n < 4; ++n)
            acc[m][n] = (f32x4){0.f, 0.f, 0.f, 0.f};

    bf16x8 af[4][2], bf[4][2];
    #pragma unroll
    for (int m = 0; m < 4; ++m) {
        const int orow = o0 + w * 64 + m * 16 + l15;
        #pragma unroll
        for (int kk = 0; kk < 2; ++kk)
            af[m][kk] = ld_cvt8(Wo + (size_t)orow * DM + h * DK + kk * 32 + q8);
    }
    #pragma unroll
    for (int n = 0; n < 4; ++n) {
        const int d = n * 16 + l15;
        #pragma unroll
        for (int kk = 0; kk < 2; ++kk)
            bf[n][kk] = ld_cvt8(MmH + (size_t)d * DK + kk * 32 + q8);
    }
    #pragma unroll
    for (int kk = 0; kk < 2; ++kk)
        #pragma unroll
        for (int m = 0; m < 4; ++m)
            #pragma unroll
            for (int n = 0; n < 4; ++n)
                acc[m][n] = mfma_bf16(af[m][kk], bf[n][kk], acc[m][n]);

    const int cr = (lane >> 4) * 4, cc = lane & 15;
    #pragma unroll
    for (int n = 0; n < 4; ++n)
        #pragma unroll
        for (int m = 0; m < 4; ++m)
            #pragma unroll
            for (int r = 0; r < 4; ++r)
                Wf[(size_t)b * DM * DM +
                   (size_t)(o0 + w * 64 + m * 16 + cr + r) * DM +
                   h * DK + n * 16 + cc] = f2bf(acc[m][n][r]);
}

// ---------------------------------------------------------------------------
// bias2[b][o] = bo[o] - 1e9 * sum_j cvec[b*1024 + j] * Wo[o, j]
// Wave-per-o GEMV: grid 256 x 4 waves; one Wo-row read serves both batches.
// Lane loads 16 floats; 6-step butterfly reduce; lane 0 writes b=0 and b=1.
// ---------------------------------------------------------------------------
__global__ __launch_bounds__(256) void fuse_bias(
    const float* __restrict__ cvec, const float* __restrict__ Wo,
    const float* __restrict__ bo, float* __restrict__ bias2)
{
    const int w = threadIdx.x >> 6, lane = threadIdx.x & 63;
    const int o = blockIdx.x * 4 + w;
    const float* wr = Wo + (size_t)o * DM + lane * 16;
    const float* c0 = cvec + lane * 16;
    const float* c1 = cvec + DM + lane * 16;
    float s0 = 0.f, s1 = 0.f;
    #pragma unroll
    for (int u = 0; u < 4; ++u) {
        const float4 w4 = *reinterpret_cast<const float4*>(wr + u * 4);
        const float4 a4 = *reinterpret_cast<const float4*>(c0 + u * 4);
        const float4 b4 = *reinterpret_cast<const float4*>(c1 + u * 4);
        s0 += w4.x * a4.x + w4.y * a4.y + w4.z * a4.z + w4.w * a4.w;
        s1 += w4.x * b4.x + w4.y * b4.y + w4.z * b4.z + w4.w * b4.w;
    }
    #pragma unroll
    for (int d = 32; d >= 1; d >>= 1) {
        s0 += __shfl_xor(s0, d, 64);
        s1 += __shfl_xor(s1, d, 64);
    }
    if (lane == 0) {
        const float bv = bo[o];
        bias2[o]      = bv - 1.0e9f * s0;
        bias2[DM + o] = bv - 1.0e9f * s1;
    }
}

// ---------------------------------------------------------------------------
extern "C" void kernel_launch(void* const* d_in, const int* in_sizes, int n_in,
                              void* d_out, int out_size, void* d_ws, size_t ws_size,
                              hipStream_t stream)
{
    const float* q    = (const float*)d_in[0];
    const float* k    = (const float*)d_in[1];
    const float* v    = (const float*)d_in[2];
    const int*   mask = (const int*)  d_in[3];
    const float* Wq   = (const float*)d_in[4];
    const float* bq   = (const float*)d_in[5];
    const float* Wk   = (const float*)d_in[6];
    const float* bk   = (const float*)d_in[7];
    const float* Wv   = (const float*)d_in[8];
    const float* bv   = (const float*)d_in[9];
    const float* Wo   = (const float*)d_in[10];
    const float* bo   = (const float*)d_in[11];
    float* out = (float*)d_out;

    const int BS = in_sizes[0] / DM;   // B*S = 4096
    const int B  = 2;
    const int S  = BS / B;             // 2048
    const int BH = B * NH;             // 32
    const int SCHUNK = 64;
    const int NCHUNK = S / SCHUNK;     // 32
    const size_t BSDM = (size_t)BS * DM;   // 4M
    const size_t DMDM = (size_t)DM * DM;   // 1M

    unsigned short* ws = (unsigned short*)d_ws;
    unsigned short* qb   = ws;
    unsigned short* kb   = qb  + BSDM;
    unsigned short* vb   = kb  + BSDM;
    unsigned short* Wqb  = vb  + BSDM;
    unsigned short* Wkb  = Wqb + DMDM;
    unsigned short* Wvb  = Wkb + DMDM;
    unsigned short* Qp   = Wvb + DMDM;
    unsigned short* Kp   = Qp  + BSDM;
    unsigned short* Vp   = Kp  + BSDM;
    // aliases (dead after QKV projections):
    float* Mpart = (float*)kb;                 // 4M floats over kb+vb
    float* cvprt = (float*)Wqb;                // 64K floats
    float* Mm    = cvprt + (size_t)NCHUNK * BH * DK;       // 128K floats
    float* cvec  = Mm    + (size_t)BH * DK * DK;           // 2K floats
    unsigned short* Wf = qb;                   // 2M us (2 x 1024 x 1024 bf16)
    float* bias2 = (float*)Wkb;                // 2K floats

    const dim3 blk(256);

    // fp32 -> bf16: q,k,v (12 x 1M) + Wq,Wk,Wv (3 x 1M)
    CvtArgs cv;
    for (int i = 0; i < 4; ++i) { cv.src[0 + i] = q + (size_t)i * DMDM; cv.dst[0 + i] = qb + (size_t)i * DMDM; }
    for (int i = 0; i < 4; ++i) { cv.src[4 + i] = k + (size_t)i * DMDM; cv.dst[4 + i] = kb + (size_t)i * DMDM; }
    for (int i = 0; i < 4; ++i) { cv.src[8 + i] = v + (size_t)i * DMDM; cv.dst[8 + i] = vb + (size_t)i * DMDM; }
    cv.src[12] = Wq; cv.dst[12] = Wqb;
    cv.src[13] = Wk; cv.dst[13] = Wkb;
    cv.src[14] = Wv; cv.dst[14] = Wvb;
    cvt15<<<dim3(15 * 1024), blk, 0, stream>>>(cv);

    // batched QKV projections: 128^2-tile ring kernel, grid (256, 3) = 768 blocks
    GKArgs<unsigned short> ga;
    ga.A[0] = qb;  ga.A[1] = kb;  ga.A[2] = vb;
    ga.Wlo[0] = ga.Whi[0] = Wqb;
    ga.Wlo[1] = ga.Whi[1] = Wkb;
    ga.Wlo[2] = ga.Whi[2] = Wvb;
    ga.blo[0] = ga.bhi[0] = bq;
    ga.blo[1] = ga.bhi[1] = bk;
    ga.blo[2] = ga.bhi[2] = bv;
    ga.C[0] = Qp;  ga.C[1] = Kp;  ga.C[2] = Vp;
    gemmk<unsigned short><<<dim3((DM / 128) * (BS / 128), 3), dim3(512), 0, stream>>>(
        ga, BS, DM, DM, DM / 128, 1 << 30);

    // per-head K^T V partials + reduction
    ktv_partial<<<dim3(BH, NCHUNK), blk, 0, stream>>>(Kp, Vp, mask, Mpart, cvprt, S, SCHUNK);
    reduce_m<<<dim3(BH, 8), blk, 0, stream>>>(Mpart, cvprt, Mm, cvec, NCHUNK, BH);

    // fold Mm into Wo (per batch) + fold mask-correction into bias
    fuse_w<<<dim3(DM / 256, NH, B), blk, 0, stream>>>(Mm, Wo, Wf);
    fuse_bias<<<dim3(DM / 4), blk, 0, stream>>>(cvec, Wo, bo, bias2);

    // out = Qp @ Wf[b]^T + bias2[b]: same kernel, grid (256, 1), row-split at S
    GKArgs<float> gf;
    gf.A[0] = Qp;
    gf.Wlo[0] = Wf;        gf.Whi[0] = Wf + DMDM;
    gf.blo[0] = bias2;     gf.bhi[0] = bias2 + DM;
    gf.C[0] = out;
    gf.A[1] = gf.A[2] = nullptr;
    gf.Wlo[1] = gf.Wlo[2] = gf.Whi[1] = gf.Whi[2] = nullptr;
    gf.blo[1] = gf.blo[2] = gf.bhi[1] = gf.bhi[2] = nullptr;
    gf.C[1] = gf.C[2] = nullptr;
    gemmk<float><<<dim3((DM / 128) * (BS / 128), 1), dim3(512), 0, stream>>>(
        gf, BS, DM, DM, DM / 128, S);
}